// Round 1
// baseline (32.195 us; speedup 1.0000x reference)
//
#include <hip/hip_runtime.h>

#define BSZ 4
#define CH  64
#define CE  8      // C/8
#define HW  4096
#define NOUT 80    // 8 (k) + 8 (q_l) + 64 (v) packed output channels

// ---------------------------------------------------------------------------
// Kernel 1: fused 1x1 convolutions.
// Produces k[b,8,hw], qlT[b,8,hw] (q_l stored channel-major), v[b,64,hw].
// Block = 320 threads = 5 waves; wave g computes packed output channels
// [16g, 16g+16) for 64 adjacent columns. Grid = 256 blocks (64 per batch).
// ---------------------------------------------------------------------------
__global__ __launch_bounds__(320) void proj_kernel(
    const float* __restrict__ x,
    const float* __restrict__ qlw, const float* __restrict__ qlb,
    const float* __restrict__ kw,  const float* __restrict__ kb,
    const float* __restrict__ vw,  const float* __restrict__ vb,
    float* __restrict__ kbuf, float* __restrict__ qlbuf, float* __restrict__ vbuf)
{
    __shared__ float s_w[NOUT * CH];
    __shared__ float s_b[NOUT];
    const int tid = threadIdx.x;

    for (int i = tid; i < NOUT * CH; i += 320) {
        const int o = i >> 6, c = i & 63;
        float w;
        if (o < 8)       w = kw[o * CH + c];
        else if (o < 16) w = qlw[(o - 8) * CH + c];
        else             w = vw[(o - 16) * CH + c];
        s_w[i] = w;
    }
    if (tid < NOUT) {
        const int o = tid;
        s_b[o] = (o < 8) ? kb[o] : (o < 16 ? qlb[o - 8] : vb[o - 16]);
    }
    __syncthreads();

    const int b = blockIdx.x >> 6;
    const int p = ((blockIdx.x & 63) << 6) | (tid & 63);
    const int g = tid >> 6;          // wave id 0..4

    float xv[CH];
#pragma unroll
    for (int c = 0; c < CH; ++c) xv[c] = x[(b * CH + c) * HW + p];

    const int o0 = g * 16;
#pragma unroll
    for (int oi = 0; oi < 16; ++oi) {
        const int o = o0 + oi;       // wave-uniform
        float acc = s_b[o];
#pragma unroll
        for (int c = 0; c < CH; ++c) acc += s_w[o * CH + c] * xv[c];
        if (o < 8)       kbuf [(b * CE + o) * HW + p] = acc;
        else if (o < 16) qlbuf[(b * CE + (o - 8)) * HW + p] = acc;
        else             vbuf [(b * CH + (o - 16)) * HW + p] = acc;
    }
}

// ---------------------------------------------------------------------------
// Kernel 2: A[b,c,e] = sum_q v[b,c,q]*qg_w[q,e]
//           B[b,c,e] = sum_q v[b,c,q]*k[b,e,q]
//           s[b,c]   = sum_q v[b,c,q]*qg_b[q]
// One block per (b,c); 256 threads reduce over q.
// ---------------------------------------------------------------------------
__global__ __launch_bounds__(256) void reduce_kernel(
    const float* __restrict__ vbuf, const float* __restrict__ kbuf,
    const float* __restrict__ qgw,  const float* __restrict__ qgb,
    float* __restrict__ Abuf, float* __restrict__ Bbuf, float* __restrict__ Sbuf)
{
    const int bc = blockIdx.x;       // b*64 + c
    const int b  = bc >> 6;
    const int tid = threadIdx.x;
    const float* vrow = vbuf + (size_t)bc * HW;
    const float* krow = kbuf + (size_t)b * CE * HW;

    float accA[8] = {0, 0, 0, 0, 0, 0, 0, 0};
    float accB[8] = {0, 0, 0, 0, 0, 0, 0, 0};
    float accS = 0.f;

    for (int q = tid; q < HW; q += 256) {
        const float vv = vrow[q];
        const float4 g0 = *reinterpret_cast<const float4*>(qgw + q * 8);
        const float4 g1 = *reinterpret_cast<const float4*>(qgw + q * 8 + 4);
        accA[0] += vv * g0.x; accA[1] += vv * g0.y;
        accA[2] += vv * g0.z; accA[3] += vv * g0.w;
        accA[4] += vv * g1.x; accA[5] += vv * g1.y;
        accA[6] += vv * g1.z; accA[7] += vv * g1.w;
        accS += vv * qgb[q];
#pragma unroll
        for (int e = 0; e < 8; ++e) accB[e] += vv * krow[e * HW + q];
    }

    __shared__ float red[4][17];
    const int lane = tid & 63, wave = tid >> 6;
#pragma unroll
    for (int e = 0; e < 8; ++e) {
        float r = accA[e];
        for (int off = 32; off >= 1; off >>= 1) r += __shfl_down(r, off, 64);
        if (lane == 0) red[wave][e] = r;
    }
#pragma unroll
    for (int e = 0; e < 8; ++e) {
        float r = accB[e];
        for (int off = 32; off >= 1; off >>= 1) r += __shfl_down(r, off, 64);
        if (lane == 0) red[wave][8 + e] = r;
    }
    {
        float r = accS;
        for (int off = 32; off >= 1; off >>= 1) r += __shfl_down(r, off, 64);
        if (lane == 0) red[wave][16] = r;
    }
    __syncthreads();
    if (tid < 17) {
        const float r = red[0][tid] + red[1][tid] + red[2][tid] + red[3][tid];
        if (tid < 8)       Abuf[bc * 8 + tid] = r;
        else if (tid < 16) Bbuf[bc * 8 + (tid - 8)] = r;
        else               Sbuf[bc] = r;
    }
}

// ---------------------------------------------------------------------------
// Kernel 3: out[b,c,p] = gg*(dot8(k_g[b,p,:],A[b,c,:]) + s[b,c])
//                      + gl* dot8(q_l[b,p,:],B[b,c,:]) + x[b,c,p]
// k_g[b,p,e] = flat k buffer at b*32768 + p*8 + e (raw reshape regroup).
// Block = 256 threads = 64 columns x 4 channel-groups; grid = 256 blocks.
// ---------------------------------------------------------------------------
__global__ __launch_bounds__(256) void final_kernel(
    const float* __restrict__ x,
    const float* __restrict__ kbuf, const float* __restrict__ qlbuf,
    const float* __restrict__ Abuf, const float* __restrict__ Bbuf,
    const float* __restrict__ Sbuf,
    const float* __restrict__ ggp, const float* __restrict__ glp,
    float* __restrict__ out)
{
    __shared__ float sA[CH * 8], sB[CH * 8], sS[CH];
    const int tid = threadIdx.x;
    const int b   = blockIdx.x >> 6;
    const int p   = ((blockIdx.x & 63) << 6) | (tid & 63);
    const int grp = tid >> 6;        // channels [grp*16, grp*16+16)

    for (int i = tid; i < CH * 8; i += 256) {
        sA[i] = Abuf[b * CH * 8 + i];
        sB[i] = Bbuf[b * CH * 8 + i];
    }
    if (tid < CH) sS[tid] = Sbuf[b * CH + tid];
    __syncthreads();

    const float gg = ggp[0], gl = glp[0];

    const float* kgp = kbuf + (size_t)b * CE * HW + (size_t)p * 8;
    const float4 kg0 = *reinterpret_cast<const float4*>(kgp);
    const float4 kg1 = *reinterpret_cast<const float4*>(kgp + 4);
    const float kg[8] = {kg0.x, kg0.y, kg0.z, kg0.w, kg1.x, kg1.y, kg1.z, kg1.w};
    float ql[8];
#pragma unroll
    for (int e = 0; e < 8; ++e) ql[e] = qlbuf[(b * CE + e) * HW + p];

    const int c0 = grp * 16;
#pragma unroll
    for (int ci = 0; ci < 16; ++ci) {
        const int c = c0 + ci;       // wave-uniform
        float aA = 0.f, aB = 0.f;
#pragma unroll
        for (int e = 0; e < 8; ++e) {
            aA += kg[e] * sA[c * 8 + e];
            aB += ql[e] * sB[c * 8 + e];
        }
        const int idx = (b * CH + c) * HW + p;
        out[idx] = gg * (aA + sS[c]) + gl * aB + x[idx];
    }
}

extern "C" void kernel_launch(void* const* d_in, const int* in_sizes, int n_in,
                              void* d_out, int out_size, void* d_ws, size_t ws_size,
                              hipStream_t stream) {
    const float* x   = (const float*)d_in[0];
    const float* qlw = (const float*)d_in[1];
    const float* qlb = (const float*)d_in[2];
    const float* kw  = (const float*)d_in[3];
    const float* kb  = (const float*)d_in[4];
    const float* vw  = (const float*)d_in[5];
    const float* vb  = (const float*)d_in[6];
    const float* qgw = (const float*)d_in[7];
    const float* qgb = (const float*)d_in[8];
    const float* gg  = (const float*)d_in[9];
    const float* gl  = (const float*)d_in[10];
    float* out = (float*)d_out;

    float* ws    = (float*)d_ws;
    float* vbuf  = ws;                        // 4*64*4096  = 1048576 f
    float* kbuf  = vbuf + BSZ * CH * HW;      // 4*8*4096   =  131072 f
    float* qlbuf = kbuf + BSZ * CE * HW;      // 4*8*4096   =  131072 f
    float* Abuf  = qlbuf + BSZ * CE * HW;     // 4*64*8     =    2048 f
    float* Bbuf  = Abuf + BSZ * CH * 8;       // 4*64*8     =    2048 f
    float* Sbuf  = Bbuf + BSZ * CH * 8;       // 4*64       =     256 f
    // total ~5.26 MB of workspace

    proj_kernel<<<256, 320, 0, stream>>>(x, qlw, qlb, kw, kb, vw, vb,
                                         kbuf, qlbuf, vbuf);
    reduce_kernel<<<256, 256, 0, stream>>>(vbuf, kbuf, qgw, qgb,
                                           Abuf, Bbuf, Sbuf);
    final_kernel<<<256, 256, 0, stream>>>(x, kbuf, qlbuf, Abuf, Bbuf, Sbuf,
                                          gg, gl, out);
}